// Round 3
// baseline (146.095 us; speedup 1.0000x reference)
//
#include <hip/hip_runtime.h>

typedef float f32x4 __attribute__((ext_vector_type(4)));
typedef __bf16 bf16x8 __attribute__((ext_vector_type(8)));
typedef unsigned short u16x4 __attribute__((ext_vector_type(4)));

constexpr int V = 4096;

__device__ __forceinline__ unsigned short f2bf(float f) {
    unsigned int u = __float_as_uint(f);
    u += 0x7FFFu + ((u >> 16) & 1u);           // round-to-nearest-even
    return (unsigned short)(u >> 16);
}

// ---- kernel 1: z = W @ xv + b  -> bf16 (384 x 4096) --------------------
__global__ __launch_bounds__(256) void k_z(const float* __restrict__ x,
                                           const float* __restrict__ W,
                                           const float* __restrict__ b,
                                           unsigned short* __restrict__ zb) {
    __shared__ float Ws[8 * 128];
    __shared__ float bs[8];
    const int rg = blockIdx.x;
    const int vb = blockIdx.y;
    const int t  = threadIdx.x;
    reinterpret_cast<f32x4*>(Ws)[t] = reinterpret_cast<const f32x4*>(W + rg * 1024)[t];
    if (t < 8) bs[t] = b[rg * 8 + t];
    __syncthreads();
    const int v = vb * 1024 + t * 4;
    f32x4 acc[8] = {};
    #pragma unroll 8
    for (int j = 0; j < 128; ++j) {
        f32x4 xv = *reinterpret_cast<const f32x4*>(x + (size_t)j * V + v);
        #pragma unroll
        for (int q = 0; q < 8; ++q) acc[q] += Ws[q * 128 + j] * xv;
    }
    #pragma unroll
    for (int q = 0; q < 8; ++q) {
        u16x4 u;
        #pragma unroll
        for (int j = 0; j < 4; ++j) u[j] = f2bf(acc[q][j] + bs[q]);
        *reinterpret_cast<u16x4*>(zb + (size_t)(rg * 8 + q) * V + v) = u;
    }
}

// ---- kernel 2 (fused): two block roles sharing HBM bandwidth ----------
// role A (768 blocks): partial[p,kh] = z[p] @ A[p][k-half]   (round-1 body)
// role B (128 blocks): fsum = x + sum(fifo[:16] over i,p)    (pure streaming)
__global__ __launch_bounds__(256) void k_fused(const unsigned short* __restrict__ zb,
                                               const float* __restrict__ A,
                                               const float* __restrict__ x,
                                               const float* __restrict__ fifo,
                                               float* __restrict__ partial,
                                               float* __restrict__ fsum) {
    __shared__ unsigned short Bt[32][72];   // role A only: [n][k] bf16, pitch 72
    const int bid = blockIdx.x;
    const int t   = threadIdx.x;

    if (bid % 7 == 3) {
        // ---------------- role B: fifo streaming sum ----------------
        const int rid = bid / 7;                       // 0..127
        const size_t off  = (size_t)rid * 4096 + (size_t)t * 16;
        const size_t slab = (size_t)128 * V;
        f32x4 e0 = *reinterpret_cast<const f32x4*>(x + off);
        f32x4 e1 = *reinterpret_cast<const f32x4*>(x + off + 4);
        f32x4 e2 = *reinterpret_cast<const f32x4*>(x + off + 8);
        f32x4 e3 = *reinterpret_cast<const f32x4*>(x + off + 12);
        f32x4 o0 = {}, o1 = {}, o2 = {}, o3 = {};
        #pragma unroll
        for (int s = 0; s < 48; s += 2) {
            const float* f0 = fifo + (size_t)s * slab + off;
            const float* f1 = fifo + (size_t)(s + 1) * slab + off;
            e0 += *reinterpret_cast<const f32x4*>(f0);
            e1 += *reinterpret_cast<const f32x4*>(f0 + 4);
            e2 += *reinterpret_cast<const f32x4*>(f0 + 8);
            e3 += *reinterpret_cast<const f32x4*>(f0 + 12);
            o0 += *reinterpret_cast<const f32x4*>(f1);
            o1 += *reinterpret_cast<const f32x4*>(f1 + 4);
            o2 += *reinterpret_cast<const f32x4*>(f1 + 8);
            o3 += *reinterpret_cast<const f32x4*>(f1 + 12);
        }
        *reinterpret_cast<f32x4*>(fsum + off)      = e0 + o0;
        *reinterpret_cast<f32x4*>(fsum + off + 4)  = e1 + o1;
        *reinterpret_cast<f32x4*>(fsum + off + 8)  = e2 + o2;
        *reinterpret_cast<f32x4*>(fsum + off + 12) = e3 + o3;
        return;
    }

    // ---------------- role A: bf16 MFMA gemm (round-1 body) ----------------
    const int aid = bid - (bid + 3) / 7;     // 0..767
    const int nt  = aid & 127;
    const int pk  = aid >> 7;                // 0..5
    const int p   = pk >> 1;
    const int kh  = pk & 1;
    const int n0 = nt * 32;
    const int kbase = kh * 2048;
    const int wid  = t >> 6;
    const int lane = t & 63;
    const int lrow = lane & 15;
    const int g    = lane >> 4;

    const float* Ap = A + (size_t)p * V * V;
    const unsigned short* Zw = zb + ((size_t)p * 128 + wid * 32) * V;

    const int kk = t >> 2;      // staging row 0..63
    const int c4 = t & 3;       // staging col-quad

    f32x4 acc00 = {}, acc01 = {}, acc10 = {}, acc11 = {};

    for (int k0 = kbase; k0 < kbase + 2048; k0 += 64) {
        const float* src = Ap + (size_t)(k0 + kk) * V + n0 + c4 * 4;
        f32x4 av0 = *reinterpret_cast<const f32x4*>(src);
        f32x4 av1 = *reinterpret_cast<const f32x4*>(src + 16);
        __syncthreads();                       // previous iter's reads done
        #pragma unroll
        for (int j = 0; j < 4; ++j) {
            Bt[c4 * 4 + j][kk]      = f2bf(av0[j]);
            Bt[16 + c4 * 4 + j][kk] = f2bf(av1[j]);
        }
        __syncthreads();                       // tile visible
        const unsigned short* zrow = Zw + (size_t)lrow * V + k0 + g * 8;
        #pragma unroll
        for (int ks = 0; ks < 2; ++ks) {
            bf16x8 b0 = *reinterpret_cast<const bf16x8*>(&Bt[lrow][ks * 32 + g * 8]);
            bf16x8 b1 = *reinterpret_cast<const bf16x8*>(&Bt[16 + lrow][ks * 32 + g * 8]);
            bf16x8 a0 = *reinterpret_cast<const bf16x8*>(zrow + ks * 32);
            bf16x8 a1 = *reinterpret_cast<const bf16x8*>(zrow + (size_t)16 * V + ks * 32);
            acc00 = __builtin_amdgcn_mfma_f32_16x16x32_bf16(a0, b0, acc00, 0, 0, 0);
            acc01 = __builtin_amdgcn_mfma_f32_16x16x32_bf16(a0, b1, acc01, 0, 0, 0);
            acc10 = __builtin_amdgcn_mfma_f32_16x16x32_bf16(a1, b0, acc10, 0, 0, 0);
            acc11 = __builtin_amdgcn_mfma_f32_16x16x32_bf16(a1, b1, acc11, 0, 0, 0);
        }
    }

    // C/D layout: col = lane&15, row = (lane>>4)*4 + reg   [verified m89/m91]
    float* Pp = partial + (size_t)pk * 128 * V;
    #pragma unroll
    for (int r = 0; r < 4; ++r) {
        const int m0 = wid * 32 + g * 4 + r;
        Pp[(size_t)m0 * V + n0 + lrow]             = acc00[r];
        Pp[(size_t)m0 * V + n0 + 16 + lrow]        = acc01[r];
        Pp[(size_t)(m0 + 16) * V + n0 + lrow]      = acc10[r];
        Pp[(size_t)(m0 + 16) * V + n0 + 16 + lrow] = acc11[r];
    }
}

// ---- kernel 3: out = relu(sum(partials) + fsum) ------------------------
__global__ __launch_bounds__(256) void k_epi2(const float* __restrict__ partial,
                                              const float* __restrict__ fsum,
                                              float* __restrict__ out) {
    const size_t off  = ((size_t)blockIdx.x * 256 + threadIdx.x) * 4;
    const size_t slab = (size_t)128 * V;
    f32x4 s0 = *reinterpret_cast<const f32x4*>(fsum + off);
    f32x4 s1 = {};
    #pragma unroll
    for (int q = 0; q < 6; ++q) {
        f32x4 pv = *reinterpret_cast<const f32x4*>(partial + (size_t)q * slab + off);
        if (q & 1) s1 += pv; else s0 += pv;
    }
    f32x4 sum = s0 + s1;
    f32x4 o;
    #pragma unroll
    for (int j = 0; j < 4; ++j) o[j] = fmaxf(sum[j], 0.0f);
    *reinterpret_cast<f32x4*>(out + off) = o;
}

extern "C" void kernel_launch(void* const* d_in, const int* in_sizes, int n_in,
                              void* d_out, int out_size, void* d_ws, size_t ws_size,
                              hipStream_t stream) {
    const float* x    = (const float*)d_in[0];   // (1,128,4096,1)
    const float* A    = (const float*)d_in[1];   // (3,4096,4096)
    const float* fifo = (const float*)d_in[2];   // (17,3,128,4096)
    const float* W    = (const float*)d_in[3];   // (384,128)
    const float* b    = (const float*)d_in[4];   // (384,)
    float* out = (float*)d_out;                  // (1,128,4096) f32

    unsigned short* zb = (unsigned short*)d_ws;                         // 3 MB bf16
    float* partial = (float*)((char*)d_ws + (size_t)3 * 1024 * 1024);   // 12 MB f32 (6 slabs)
    float* fsum    = (float*)((char*)d_ws + (size_t)15 * 1024 * 1024);  // 2 MB f32

    k_z    <<<dim3(48, 4), 256, 0, stream>>>(x, W, b, zb);
    k_fused<<<dim3(896),   256, 0, stream>>>(zb, A, x, fifo, partial, fsum);
    k_epi2 <<<dim3(512),   256, 0, stream>>>(partial, fsum, out);
}

// Round 4
// 118.403 us; speedup vs baseline: 1.2339x; 1.2339x over previous
//
#include <hip/hip_runtime.h>

typedef float f32x4 __attribute__((ext_vector_type(4)));
typedef __bf16 bf16x8 __attribute__((ext_vector_type(8)));
typedef unsigned short u16x4 __attribute__((ext_vector_type(4)));

constexpr int V = 4096;
constexpr int KSPLIT = 4;          // K split factor
constexpr int KSLAB  = V / KSPLIT; // 1024
constexpr int NSLAB  = 3 * KSPLIT; // 12 partial slabs

__device__ __forceinline__ unsigned short f2bf(float f) {
    unsigned int u = __float_as_uint(f);
    u += 0x7FFFu + ((u >> 16) & 1u);           // round-to-nearest-even
    return (unsigned short)(u >> 16);
}
__device__ __forceinline__ float bf2f(unsigned short h) {
    return __uint_as_float(((unsigned int)h) << 16);
}

// ---- kernel 1: z = W @ xv + b  -> bf16 (384 x 4096) --------------------
__global__ __launch_bounds__(256) void k_z(const float* __restrict__ x,
                                           const float* __restrict__ W,
                                           const float* __restrict__ b,
                                           unsigned short* __restrict__ zb) {
    __shared__ float Ws[8 * 128];
    __shared__ float bs[8];
    const int rg = blockIdx.x;
    const int vb = blockIdx.y;
    const int t  = threadIdx.x;
    reinterpret_cast<f32x4*>(Ws)[t] = reinterpret_cast<const f32x4*>(W + rg * 1024)[t];
    if (t < 8) bs[t] = b[rg * 8 + t];
    __syncthreads();
    const int v = vb * 1024 + t * 4;
    f32x4 acc[8] = {};
    #pragma unroll 8
    for (int j = 0; j < 128; ++j) {
        f32x4 xv = *reinterpret_cast<const f32x4*>(x + (size_t)j * V + v);
        #pragma unroll
        for (int q = 0; q < 8; ++q) acc[q] += Ws[q * 128 + j] * xv;
    }
    #pragma unroll
    for (int q = 0; q < 8; ++q) {
        u16x4 u;
        #pragma unroll
        for (int j = 0; j < 4; ++j) u[j] = f2bf(acc[q][j] + bs[q]);
        *reinterpret_cast<u16x4*>(zb + (size_t)(rg * 8 + q) * V + v) = u;
    }
}

// ---- kernel 2: partial[p,kh] = bf16( z[p] @ A[p][k-slab] ) -------------
// grid (128 n-tiles, 3 p, 4 k-slabs) = 1536 blocks (6/CU), 256 thr = 4 waves.
// Tile 128M x 32N, BK=64, single LDS buffer + 1-deep register prefetch of A.
__global__ __launch_bounds__(256) void k_gemm(const unsigned short* __restrict__ zb,
                                              const float* __restrict__ A,
                                              unsigned short* __restrict__ partial) {
    __shared__ unsigned short Bt[32][72];   // [n][k] bf16, pitch 72
    const int nt = blockIdx.x;
    const int p  = blockIdx.y;
    const int kh = blockIdx.z;
    const int n0 = nt * 32;
    const int kbase = kh * KSLAB, kend = kbase + KSLAB;
    const int t    = threadIdx.x;
    const int wid  = t >> 6;
    const int lane = t & 63;
    const int lrow = lane & 15;
    const int g    = lane >> 4;

    const float* Ap = A + (size_t)p * V * V;
    const unsigned short* Zw = zb + ((size_t)p * 128 + wid * 32) * V;

    const int kk = t >> 2;      // staging row 0..63
    const int c4 = t & 3;       // staging col-quad

    f32x4 acc00 = {}, acc01 = {}, acc10 = {}, acc11 = {};
    f32x4 av0, av1;
    {   // prologue: first A tile in flight
        const float* src = Ap + (size_t)(kbase + kk) * V + n0 + c4 * 4;
        av0 = *reinterpret_cast<const f32x4*>(src);
        av1 = *reinterpret_cast<const f32x4*>(src + 16);
    }

    for (int k0 = kbase; k0 < kend; k0 += 64) {
        __syncthreads();                       // previous iter's LDS readers done
        #pragma unroll
        for (int j = 0; j < 4; ++j) {
            Bt[c4 * 4 + j][kk]      = f2bf(av0[j]);
            Bt[16 + c4 * 4 + j][kk] = f2bf(av1[j]);
        }
        {   // issue NEXT tile now — in flight across MFMA phase + barrier
            const int kn = (k0 + 64 < kend) ? k0 + 64 : kbase;  // clamp: dead loads on last iter
            const float* src = Ap + (size_t)(kn + kk) * V + n0 + c4 * 4;
            av0 = *reinterpret_cast<const f32x4*>(src);
            av1 = *reinterpret_cast<const f32x4*>(src + 16);
        }
        __syncthreads();                       // tile visible
        const unsigned short* zrow = Zw + (size_t)lrow * V + k0 + g * 8;
        #pragma unroll
        for (int ks = 0; ks < 2; ++ks) {
            bf16x8 b0 = *reinterpret_cast<const bf16x8*>(&Bt[lrow][ks * 32 + g * 8]);
            bf16x8 b1 = *reinterpret_cast<const bf16x8*>(&Bt[16 + lrow][ks * 32 + g * 8]);
            bf16x8 a0 = *reinterpret_cast<const bf16x8*>(zrow + ks * 32);
            bf16x8 a1 = *reinterpret_cast<const bf16x8*>(zrow + (size_t)16 * V + ks * 32);
            acc00 = __builtin_amdgcn_mfma_f32_16x16x32_bf16(a0, b0, acc00, 0, 0, 0);
            acc01 = __builtin_amdgcn_mfma_f32_16x16x32_bf16(a0, b1, acc01, 0, 0, 0);
            acc10 = __builtin_amdgcn_mfma_f32_16x16x32_bf16(a1, b0, acc10, 0, 0, 0);
            acc11 = __builtin_amdgcn_mfma_f32_16x16x32_bf16(a1, b1, acc11, 0, 0, 0);
        }
    }

    // C/D layout: col = lane&15, row = (lane>>4)*4 + reg   [verified m89/m91]
    unsigned short* Pp = partial + (size_t)(p * KSPLIT + kh) * 128 * V;
    #pragma unroll
    for (int r = 0; r < 4; ++r) {
        const int m0 = wid * 32 + g * 4 + r;
        Pp[(size_t)m0 * V + n0 + lrow]             = f2bf(acc00[r]);
        Pp[(size_t)m0 * V + n0 + 16 + lrow]        = f2bf(acc01[r]);
        Pp[(size_t)(m0 + 16) * V + n0 + lrow]      = f2bf(acc10[r]);
        Pp[(size_t)(m0 + 16) * V + n0 + 16 + lrow] = f2bf(acc11[r]);
    }
}

// ---- kernel 3: out = relu(x + sum(fifo[:48 slabs]) + sum(12 bf16 partials))
__global__ __launch_bounds__(256) void k_epi(const float* __restrict__ x,
                                             const float* __restrict__ fifo,
                                             const unsigned short* __restrict__ partial,
                                             float* __restrict__ out) {
    const size_t off  = ((size_t)blockIdx.x * 256 + threadIdx.x) * 4;
    const size_t slab = (size_t)128 * V;
    f32x4 s0 = *reinterpret_cast<const f32x4*>(x + off);
    f32x4 s1 = {}, s2 = {}, s3 = {};
    #pragma unroll
    for (int s = 0; s < 48; ++s) {   // fifo[:16] x 3p = first 48 slabs
        f32x4 fv = *reinterpret_cast<const f32x4*>(fifo + (size_t)s * slab + off);
        switch (s & 3) {
            case 0: s0 += fv; break;
            case 1: s1 += fv; break;
            case 2: s2 += fv; break;
            default: s3 += fv; break;
        }
    }
    #pragma unroll
    for (int q = 0; q < NSLAB; ++q) {
        u16x4 pv = *reinterpret_cast<const u16x4*>(partial + (size_t)q * slab + off);
        f32x4 d;
        #pragma unroll
        for (int j = 0; j < 4; ++j) d[j] = bf2f(pv[j]);
        if (q & 1) s1 += d; else s2 += d;
    }
    f32x4 sum = (s0 + s1) + (s2 + s3);
    f32x4 o;
    #pragma unroll
    for (int j = 0; j < 4; ++j) o[j] = fmaxf(sum[j], 0.0f);
    *reinterpret_cast<f32x4*>(out + off) = o;
}

extern "C" void kernel_launch(void* const* d_in, const int* in_sizes, int n_in,
                              void* d_out, int out_size, void* d_ws, size_t ws_size,
                              hipStream_t stream) {
    const float* x    = (const float*)d_in[0];   // (1,128,4096,1)
    const float* A    = (const float*)d_in[1];   // (3,4096,4096)
    const float* fifo = (const float*)d_in[2];   // (17,3,128,4096)
    const float* W    = (const float*)d_in[3];   // (384,128)
    const float* b    = (const float*)d_in[4];   // (384,)
    float* out = (float*)d_out;                  // (1,128,4096) f32

    unsigned short* zb      = (unsigned short*)d_ws;                            // 3 MB bf16
    unsigned short* partial = (unsigned short*)((char*)d_ws + (size_t)3 * 1024 * 1024); // 12 MB bf16 (12 slabs)

    k_z   <<<dim3(48, 4),          256, 0, stream>>>(x, W, b, zb);
    k_gemm<<<dim3(128, 3, KSPLIT), 256, 0, stream>>>(zb, A, partial);
    k_epi <<<dim3(512),            256, 0, stream>>>(x, fifo, partial, out);
}

// Round 5
// 116.910 us; speedup vs baseline: 1.2496x; 1.0128x over previous
//
#include <hip/hip_runtime.h>

typedef float f32x4 __attribute__((ext_vector_type(4)));
typedef __bf16 bf16x8 __attribute__((ext_vector_type(8)));
typedef unsigned short u16x4 __attribute__((ext_vector_type(4)));

constexpr int V = 4096;
constexpr int KSPLIT = 4;          // K split factor
constexpr int KSLAB  = V / KSPLIT; // 1024
constexpr int NSLAB  = 3 * KSPLIT; // 12 partial slabs

__device__ __forceinline__ unsigned short f2bf(float f) {
    unsigned int u = __float_as_uint(f);
    u += 0x7FFFu + ((u >> 16) & 1u);           // round-to-nearest-even
    return (unsigned short)(u >> 16);
}
__device__ __forceinline__ float bf2f(unsigned short h) {
    return __uint_as_float(((unsigned int)h) << 16);
}

// ---- kernel 1: z = W @ xv + b  -> bf16 (384 x 4096) --------------------
__global__ __launch_bounds__(256) void k_z(const float* __restrict__ x,
                                           const float* __restrict__ W,
                                           const float* __restrict__ b,
                                           unsigned short* __restrict__ zb) {
    __shared__ float Ws[8 * 128];
    __shared__ float bs[8];
    const int rg = blockIdx.x;
    const int vb = blockIdx.y;
    const int t  = threadIdx.x;
    reinterpret_cast<f32x4*>(Ws)[t] = reinterpret_cast<const f32x4*>(W + rg * 1024)[t];
    if (t < 8) bs[t] = b[rg * 8 + t];
    __syncthreads();
    const int v = vb * 1024 + t * 4;
    f32x4 acc[8] = {};
    #pragma unroll 8
    for (int j = 0; j < 128; ++j) {
        f32x4 xv = *reinterpret_cast<const f32x4*>(x + (size_t)j * V + v);
        #pragma unroll
        for (int q = 0; q < 8; ++q) acc[q] += Ws[q * 128 + j] * xv;
    }
    #pragma unroll
    for (int q = 0; q < 8; ++q) {
        u16x4 u;
        #pragma unroll
        for (int j = 0; j < 4; ++j) u[j] = f2bf(acc[q][j] + bs[q]);
        *reinterpret_cast<u16x4*>(zb + (size_t)(rg * 8 + q) * V + v) = u;
    }
}

// ---- kernel 2: partial[p,kh] = bf16( z[p] @ A[p][k-slab] ) -------------
// grid (128 n-tiles, 3 p, 4 k-slabs) = 1536 blocks, 256 thr = 4 waves.
// Tile 128M x 32N, BK=64. Double-buffered LDS, ONE raw barrier per tile
// (counted vmcnt survives across it), A 2-deep + z 1-deep prefetch.
__global__ __launch_bounds__(256) void k_gemm(const unsigned short* __restrict__ zb,
                                              const float* __restrict__ A,
                                              unsigned short* __restrict__ partial) {
    // [buf][n(32)][k-pair(32) XOR-swizzled] u32 = {bf16 k=2r, bf16 k=2r+1}
    __shared__ unsigned int Bt[2][32][32];
    const int nt = blockIdx.x;
    const int p  = blockIdx.y;
    const int kh = blockIdx.z;
    const int n0 = nt * 32;
    const int kbase = kh * KSLAB, kend = kbase + KSLAB;
    const int t    = threadIdx.x;
    const int wid  = t >> 6;
    const int lane = t & 63;
    const int lrow = lane & 15;
    const int g    = lane >> 4;
    const int sw   = (lrow & 7) << 2;          // read-side XOR swizzle

    const int r  = t >> 3;                     // k-pair index 0..31
    const int c  = t & 7;                      // n-quad 0..7
    const int rx = r ^ ((c & 1) << 4);         // write-side swizzle base

    const float* Abase = A + (size_t)p * V * V + n0 + c * 4;
    const unsigned short* Zw = zb + ((size_t)p * 128 + wid * 32 + lrow) * V + g * 8;

    f32x4 acc00 = {}, acc01 = {}, acc10 = {}, acc11 = {};
    f32x4 avA0, avA1, avB0, avB1;
    bf16x8 zA0, zA1, zA2, zA3, zB0, zB1, zB2, zB3;

#define LOADA(d0, d1, K) { const float* s_ = Abase + (size_t)((K) + 2 * r) * V; \
        d0 = *reinterpret_cast<const f32x4*>(s_); \
        d1 = *reinterpret_cast<const f32x4*>(s_ + V); }

#define LOADZ(z0_, z1_, z2_, z3_, K) { const unsigned short* zr_ = Zw + (K); \
        z0_ = *reinterpret_cast<const bf16x8*>(zr_); \
        z1_ = *reinterpret_cast<const bf16x8*>(zr_ + (size_t)16 * V); \
        z2_ = *reinterpret_cast<const bf16x8*>(zr_ + 32); \
        z3_ = *reinterpret_cast<const bf16x8*>(zr_ + (size_t)16 * V + 32); }

    // pack two k-adjacent rows into u32 (lo = even k, hi = odd k), 4x ds_write_b32
#define WRITEB(B, a0, a1) { unsigned int u0_, u1_, u2_, u3_; \
        asm("v_cvt_pk_bf16_f32 %0, %1, %2" : "=v"(u0_) : "v"(a0[0]), "v"(a1[0])); \
        asm("v_cvt_pk_bf16_f32 %0, %1, %2" : "=v"(u1_) : "v"(a0[1]), "v"(a1[1])); \
        asm("v_cvt_pk_bf16_f32 %0, %1, %2" : "=v"(u2_) : "v"(a0[2]), "v"(a1[2])); \
        asm("v_cvt_pk_bf16_f32 %0, %1, %2" : "=v"(u3_) : "v"(a0[3]), "v"(a1[3])); \
        Bt[B][c * 4 + 0][rx ^ 0]  = u0_; \
        Bt[B][c * 4 + 1][rx ^ 4]  = u1_; \
        Bt[B][c * 4 + 2][rx ^ 8]  = u2_; \
        Bt[B][c * 4 + 3][rx ^ 12] = u3_; }

    // raw barrier: own LDS writes drained, but VMEM prefetches stay in flight
#define BAR asm volatile("s_waitcnt lgkmcnt(0)\n\ts_barrier" ::: "memory")

#define MFMAP(B, zz0, zz1, zz2, zz3) { \
        bf16x8 b0a = *reinterpret_cast<const bf16x8*>(&Bt[B][lrow]     [(g * 4) ^ sw]); \
        bf16x8 b1a = *reinterpret_cast<const bf16x8*>(&Bt[B][16 + lrow][(g * 4) ^ sw]); \
        bf16x8 b0b = *reinterpret_cast<const bf16x8*>(&Bt[B][lrow]     [(16 + g * 4) ^ sw]); \
        bf16x8 b1b = *reinterpret_cast<const bf16x8*>(&Bt[B][16 + lrow][(16 + g * 4) ^ sw]); \
        acc00 = __builtin_amdgcn_mfma_f32_16x16x32_bf16(zz0, b0a, acc00, 0, 0, 0); \
        acc01 = __builtin_amdgcn_mfma_f32_16x16x32_bf16(zz0, b1a, acc01, 0, 0, 0); \
        acc10 = __builtin_amdgcn_mfma_f32_16x16x32_bf16(zz1, b0a, acc10, 0, 0, 0); \
        acc11 = __builtin_amdgcn_mfma_f32_16x16x32_bf16(zz1, b1a, acc11, 0, 0, 0); \
        acc00 = __builtin_amdgcn_mfma_f32_16x16x32_bf16(zz2, b0b, acc00, 0, 0, 0); \
        acc01 = __builtin_amdgcn_mfma_f32_16x16x32_bf16(zz2, b1b, acc01, 0, 0, 0); \
        acc10 = __builtin_amdgcn_mfma_f32_16x16x32_bf16(zz3, b0b, acc10, 0, 0, 0); \
        acc11 = __builtin_amdgcn_mfma_f32_16x16x32_bf16(zz3, b1b, acc11, 0, 0, 0); }

    // prologue: tiles 0,1 (A) + z tile 0 in flight
    LOADA(avA0, avA1, kbase);
    LOADA(avB0, avB1, kbase + 64);
    LOADZ(zA0, zA1, zA2, zA3, kbase);

    for (int k0 = kbase; k0 < kend; k0 += 128) {
        const bool pf = (k0 + 128) < kend;
        // ---- phase A: tile k0 -> buf0 ----
        WRITEB(0, avA0, avA1);                     // waits only avA's vmcnt
        if (pf) LOADA(avA0, avA1, k0 + 128);       // 2-deep A prefetch
        LOADZ(zB0, zB1, zB2, zB3, k0 + 64);        // 1-deep z prefetch
        BAR;
        MFMAP(0, zA0, zA1, zA2, zA3);
        // ---- phase B: tile k0+64 -> buf1 ----
        WRITEB(1, avB0, avB1);
        if (pf) {
            LOADA(avB0, avB1, k0 + 192);
            LOADZ(zA0, zA1, zA2, zA3, k0 + 128);
        }
        BAR;
        MFMAP(1, zB0, zB1, zB2, zB3);
    }

    // C/D layout: col = lane&15, row = (lane>>4)*4 + reg   [verified m89/m91]
    unsigned short* Pp = partial + (size_t)(p * KSPLIT + kh) * 128 * V;
    #pragma unroll
    for (int rr = 0; rr < 4; ++rr) {
        const int m0 = wid * 32 + g * 4 + rr;
        Pp[(size_t)m0 * V + n0 + lrow]             = f2bf(acc00[rr]);
        Pp[(size_t)m0 * V + n0 + 16 + lrow]        = f2bf(acc01[rr]);
        Pp[(size_t)(m0 + 16) * V + n0 + lrow]      = f2bf(acc10[rr]);
        Pp[(size_t)(m0 + 16) * V + n0 + 16 + lrow] = f2bf(acc11[rr]);
    }
#undef LOADA
#undef LOADZ
#undef WRITEB
#undef BAR
#undef MFMAP
}

// ---- kernel 3: out = relu(x + sum(fifo[:48 slabs]) + sum(12 bf16 partials))
__global__ __launch_bounds__(256) void k_epi(const float* __restrict__ x,
                                             const float* __restrict__ fifo,
                                             const unsigned short* __restrict__ partial,
                                             float* __restrict__ out) {
    const size_t off  = ((size_t)blockIdx.x * 256 + threadIdx.x) * 4;
    const size_t slab = (size_t)128 * V;
    f32x4 s0 = *reinterpret_cast<const f32x4*>(x + off);
    f32x4 s1 = {}, s2 = {}, s3 = {};
    #pragma unroll
    for (int s = 0; s < 48; ++s) {   // fifo[:16] x 3p = first 48 slabs
        f32x4 fv = *reinterpret_cast<const f32x4*>(fifo + (size_t)s * slab + off);
        switch (s & 3) {
            case 0: s0 += fv; break;
            case 1: s1 += fv; break;
            case 2: s2 += fv; break;
            default: s3 += fv; break;
        }
    }
    #pragma unroll
    for (int q = 0; q < NSLAB; ++q) {
        u16x4 pv = *reinterpret_cast<const u16x4*>(partial + (size_t)q * slab + off);
        f32x4 d;
        #pragma unroll
        for (int j = 0; j < 4; ++j) d[j] = bf2f(pv[j]);
        if (q & 1) s1 += d; else s2 += d;
    }
    f32x4 sum = (s0 + s1) + (s2 + s3);
    f32x4 o;
    #pragma unroll
    for (int j = 0; j < 4; ++j) o[j] = fmaxf(sum[j], 0.0f);
    *reinterpret_cast<f32x4*>(out + off) = o;
}

extern "C" void kernel_launch(void* const* d_in, const int* in_sizes, int n_in,
                              void* d_out, int out_size, void* d_ws, size_t ws_size,
                              hipStream_t stream) {
    const float* x    = (const float*)d_in[0];   // (1,128,4096,1)
    const float* A    = (const float*)d_in[1];   // (3,4096,4096)
    const float* fifo = (const float*)d_in[2];   // (17,3,128,4096)
    const float* W    = (const float*)d_in[3];   // (384,128)
    const float* b    = (const float*)d_in[4];   // (384,)
    float* out = (float*)d_out;                  // (1,128,4096) f32

    unsigned short* zb      = (unsigned short*)d_ws;                                    // 3 MB bf16
    unsigned short* partial = (unsigned short*)((char*)d_ws + (size_t)3 * 1024 * 1024); // 12 MB bf16

    k_z   <<<dim3(48, 4),          256, 0, stream>>>(x, W, b, zb);
    k_gemm<<<dim3(128, 3, KSPLIT), 256, 0, stream>>>(zb, A, partial);
    k_epi <<<dim3(512),            256, 0, stream>>>(x, fifo, partial, out);
}